// Round 8
// baseline (175.253 us; speedup 1.0000x reference)
//
#include <hip/hip_runtime.h>

// VQ-VAE VectorQuantizer2 forward for MI355X (gfx950)
// z:   (8, 8, 32, 32, 32) fp32  [b, c, l, h, w], c = e_dim = 8
// emb: (1024, 8) fp32
// out: [ z_q (2097152) | loss (1) | unique (1) | idx (262144) ]  all as fp32
//
// ws layout (bytes):
//   [0,    4096)  used[1024]  int    (zeroed by vq_prep each launch)
//   [4096, 8192)  e2g[1024]   float  (||e_i||^2, by vq_prep)
//   [8192, 12288) partials[1024] float (per-block loss sums)

#define NE 1024
#define ED 8
#define NPOS 262144        // 8 * 32*32*32
#define SPAT 32768         // 32*32*32
#define CH_STRIDE 32768    // channel stride in floats
#define BATCH_STRIDE 262144// batch stride in floats (8 channels * 32768)
#define LOSS_OFF 2097152
#define UNIQ_OFF 2097153
#define IDX_OFF 2097154

__global__ __launch_bounds__(256)
void vq_prep(const float* __restrict__ emb, int* __restrict__ used,
             float* __restrict__ e2g) {
    int j = blockIdx.x * 256 + threadIdx.x;
    if (j < NE) {
        used[j] = 0;
        const float* e = emb + j * ED;
        float s;
        {
            // mul-then-add, no contraction (mirror elementwise-square+reduce)
            #pragma clang fp contract(off)
            float acc = e[0] * e[0];
            #pragma unroll
            for (int k = 1; k < ED; ++k) acc += e[k] * e[k];
            s = acc;
        }
        e2g[j] = s;
    }
}

__global__ __launch_bounds__(256)
void vq_main(const float* __restrict__ z, const float* __restrict__ emb,
             const float* __restrict__ e2g, float* __restrict__ out,
             int* __restrict__ used, float* __restrict__ partials) {
    const int tid = threadIdx.x;
    const int n = blockIdx.x * 256 + tid;
    const int b = n >> 15;          // n / 32768
    const int s = n & (SPAT - 1);   // n % 32768

    // Load this position's 8-dim vector (coalesced per channel across lanes)
    const float* zp = z + b * BATCH_STRIDE + s;
    float zv[ED];
    #pragma unroll
    for (int c = 0; c < ED; ++c) zv[c] = zp[c * CH_STRIDE];

    // ||z||^2: separate mul then add (match XLA's square-then-reduce; no fma)
    float z2;
    {
        #pragma clang fp contract(off)
        float acc = zv[0] * zv[0];
        #pragma unroll
        for (int c = 1; c < ED; ++c) acc += zv[c] * zv[c];
        z2 = acc;
    }

    // Scan all 1024 codes. Codebook addresses are wave-uniform -> scalar-pipe
    // s_load (constant cache); zero VALU/LDS cost for operand fetch.
    const float4* cb4 = (const float4*)emb;
    float best = 3.4e38f;
    int bi = 0;
    #pragma unroll 8
    for (int i = 0; i < NE; ++i) {
        const float4 ea = cb4[2 * i];
        const float4 eb = cb4[2 * i + 1];
        const float e2 = e2g[i];
        // sequential FMA chain, ascending k, acc from 0 (mirror gemm K-loop)
        float dot = zv[0] * ea.x;            // == fma(z0,e0,0)
        dot = fmaf(zv[1], ea.y, dot);
        dot = fmaf(zv[2], ea.z, dot);
        dot = fmaf(zv[3], ea.w, dot);
        dot = fmaf(zv[4], eb.x, dot);
        dot = fmaf(zv[5], eb.y, dot);
        dot = fmaf(zv[6], eb.z, dot);
        dot = fmaf(zv[7], eb.w, dot);
        // d = (z2 + e2) - 2*dot ; 2*dot is exact => fmaf rounds identically
        const float d = fmaf(-2.0f, dot, z2 + e2);
        if (d < best) { best = d; bi = i; }  // strict < => first-min tiebreak
    }

    // Gather winning code (non-uniform; 32KB table stays L1/L2-hot)
    const float4 wa = cb4[2 * bi];
    const float4 wb = cb4[2 * bi + 1];
    float ev[ED] = {wa.x, wa.y, wa.z, wa.w, wb.x, wb.y, wb.z, wb.w};

    // Write z_q (same layout as z) + accumulate loss contribution
    float* outq = out + b * BATCH_STRIDE + s;
    float lacc = 0.0f;
    #pragma unroll
    for (int c = 0; c < ED; ++c) {
        const float diff = ev[c] - zv[c];
        lacc = fmaf(diff, diff, lacc);
        outq[c * CH_STRIDE] = ev[c];
    }

    out[IDX_OFF + n] = (float)bi;
    used[bi] = 1;   // benign race: same value from all writers

    // Deterministic block-tree reduction of loss partial (graph replay must
    // revalidate bit-identically -> no float atomics)
    __shared__ float red[256];
    red[tid] = lacc;
    __syncthreads();
    #pragma unroll
    for (int off = 128; off > 0; off >>= 1) {
        if (tid < off) red[tid] += red[tid + off];
        __syncthreads();
    }
    if (tid == 0) partials[blockIdx.x] = red[0];
}

__global__ __launch_bounds__(1024)
void vq_final(const float* __restrict__ partials, const int* __restrict__ used,
              float* __restrict__ out) {
    __shared__ float sred[1024];
    __shared__ int ured[1024];
    const int t = threadIdx.x;
    sred[t] = partials[t];
    ured[t] = used[t] ? 1 : 0;
    __syncthreads();
    for (int off = 512; off > 0; off >>= 1) {
        if (t < off) { sred[t] += sred[t + off]; ured[t] += ured[t + off]; }
        __syncthreads();
    }
    if (t == 0) {
        const float M = sred[0] * (1.0f / 2097152.0f);  // exact pow2 scale
        out[LOSS_OFF] = 0.25f * M + M;   // beta*mean + mean (forward values equal)
        out[UNIQ_OFF] = (float)ured[0];
    }
}

extern "C" void kernel_launch(void* const* d_in, const int* in_sizes, int n_in,
                              void* d_out, int out_size, void* d_ws, size_t ws_size,
                              hipStream_t stream) {
    const float* z   = (const float*)d_in[0];
    const float* emb = (const float*)d_in[1];
    float* out = (float*)d_out;

    int*   used     = (int*)d_ws;
    float* e2g      = (float*)((char*)d_ws + 4096);
    float* partials = (float*)((char*)d_ws + 8192);

    vq_prep<<<4, 256, 0, stream>>>(emb, used, e2g);
    vq_main<<<NPOS / 256, 256, 0, stream>>>(z, emb, e2g, out, used, partials);
    vq_final<<<1, 1024, 0, stream>>>(partials, used, out);
}